// Round 7
// baseline (148.833 us; speedup 1.0000x reference)
//
#include <hip/hip_runtime.h>

// ChamferLossSelf: B=4, N=4096, D=3, fp32 in/out. out = loss1 + loss2 + ALPHA*ordering.
constexpr int BATCH = 4;
constexpr int NPTS  = 4096;
constexpr int TILE  = 128;          // rows per block; cols per chunk
constexpr int NCH   = NPTS / TILE;  // 32 col-chunks
constexpr int NTHR  = 512;

// ws: float nnmin[4][BATCH][NPTS] — every element direct-stored by nn_pass (no init needed)
// slot0: per-gts NN dist among preds  -> loss_2
// slot1: per-pred NN dist among gts   -> loss_1
// slot2: gts self-NN (diag excluded)  -> mins1
// slot3: preds self-NN (diag excluded)-> mins2

__global__ __launch_bounds__(NTHR, 4) void nn_pass(const float* __restrict__ gts,
                                                   const float* __restrict__ preds,
                                                   float* __restrict__ nnmin) {
    const int I    = blockIdx.x;   // row-stripe
    const int pass = blockIdx.y;   // 0..3
    const int b    = blockIdx.z;
    const float* __restrict__ A = (pass == 0 || pass == 2) ? gts : preds;  // rows
    const float* __restrict__ T = (pass == 0 || pass == 3) ? preds : gts;  // cols
    const bool self = pass >= 2;
    float* __restrict__ slot = nnmin + ((size_t)pass * BATCH + b) * NPTS;

    const int tid = threadIdx.x;
    const int tx  = tid & 15;   // col-group: cols tx*8 .. tx*8+7
    const int ty  = tid >> 4;   // row-group: rows ty*4 .. ty*4+3 (0..31)

    // A fragment: 4 rows = 12 contiguous floats, start index 3*(b*4096+I*128+ty*4) ≡ 0 mod 4
    const float* aptr = A + ((size_t)b * NPTS + I * TILE + ty * 4) * 3;
    const float4 a0 = reinterpret_cast<const float4*>(aptr)[0];  // x0 y0 z0 x1
    const float4 a1 = reinterpret_cast<const float4*>(aptr)[1];  // y1 z1 x2 y2
    const float4 a2 = reinterpret_cast<const float4*>(aptr)[2];  // z2 x3 y3 z3
    const float ax[4] = {a0.x, a0.w, a1.z, a2.y};
    const float ay[4] = {a0.y, a1.x, a1.w, a2.z};
    const float az[4] = {a0.z, a1.y, a2.x, a2.w};

    // B staging: SoA, 16 groups of 8 cols at stride 12 (48 B: 16B-aligned b128 reads,
    // group starts span 8 distinct bank-quads -> worst 2-way conflict = free)
    __shared__ float bst[2][3][192];  // 4.6 KB

    auto stage = [&](int ch, int buf) {
        if (tid < 96) {  // 128 points * 3 = 384 floats = 96 float4 (16B-aligned)
            const float4 v = reinterpret_cast<const float4*>(
                T + ((size_t)b * NPTS + ch * TILE) * 3)[tid];
            const int f0 = tid * 4;
#pragma unroll
            for (int e = 0; e < 4; ++e) {
                const int f = f0 + e;
                const int p = f / 3, comp = f - 3 * p;
                bst[buf][comp][12 * (p >> 3) + (p & 7)] = (&v.x)[e];
            }
        }
    };

    stage(0, 0);
    __syncthreads();

    float rmin[4] = {1e30f, 1e30f, 1e30f, 1e30f};

    for (int ch = 0; ch < NCH; ++ch) {
        const int buf = ch & 1;
        if (ch + 1 < NCH) stage(ch + 1, buf ^ 1);

        // B fragments: 6x ds_read_b128, conflict-free
        const float4 x0 = *(const float4*)&bst[buf][0][12 * tx];
        const float4 x1 = *(const float4*)&bst[buf][0][12 * tx + 4];
        const float4 y0 = *(const float4*)&bst[buf][1][12 * tx];
        const float4 y1 = *(const float4*)&bst[buf][1][12 * tx + 4];
        const float4 z0 = *(const float4*)&bst[buf][2][12 * tx];
        const float4 z1 = *(const float4*)&bst[buf][2][12 * tx + 4];
        const float bx[8] = {x0.x, x0.y, x0.z, x0.w, x1.x, x1.y, x1.z, x1.w};
        const float by[8] = {y0.x, y0.y, y0.z, y0.w, y1.x, y1.y, y1.z, y1.w};
        const float bz[8] = {z0.x, z0.y, z0.z, z0.w, z1.x, z1.y, z1.z, z1.w};

        if (self && ch == I) {  // diag chunk: mask local row == local col
#pragma unroll
            for (int r = 0; r < 4; ++r) {
                const int lr = ty * 4 + r;
#pragma unroll
                for (int c = 0; c < 8; ++c) {
                    const float dx = ax[r] - bx[c];
                    const float dy = ay[r] - by[c];
                    const float dz = az[r] - bz[c];
                    float d = fmaf(dz, dz, fmaf(dy, dy, dx * dx));
                    d = (lr == tx * 8 + c) ? 1e30f : d;
                    rmin[r] = fminf(rmin[r], d);
                }
            }
        } else {
#pragma unroll
            for (int r = 0; r < 4; ++r) {
#pragma unroll
                for (int c = 0; c < 8; ++c) {
                    const float dx = ax[r] - bx[c];
                    const float dy = ay[r] - by[c];
                    const float dz = az[r] - bz[c];
                    const float d = fmaf(dz, dz, fmaf(dy, dy, dx * dx));
                    rmin[r] = fminf(rmin[r], d);
                }
            }
        }
        __syncthreads();  // stage(ch+1) done; buf free for overwrite next iter
    }

    // reduce across tx: 16 consecutive lanes (lane = (ty&3)*16 + tx)
#pragma unroll
    for (int r = 0; r < 4; ++r) {
        float m = rmin[r];
        m = fminf(m, __shfl_xor(m, 1, 64));
        m = fminf(m, __shfl_xor(m, 2, 64));
        m = fminf(m, __shfl_xor(m, 4, 64));
        m = fminf(m, __shfl_xor(m, 8, 64));
        rmin[r] = m;
    }
    if (tx == 0) {
#pragma unroll
        for (int r = 0; r < 4; ++r)
            slot[I * TILE + ty * 4 + r] = rmin[r];
    }
}

// 4 blocks (one per batch), 1024 threads: cross sums + dual bitonic sort + ordering + out.
// Sort: 4 elems/thread/array in registers; j<=2 in-thread, j in [4,128] shfl_xor, j>=256 LDS.
__global__ __launch_bounds__(1024) void nn_final(const float* __restrict__ nnmin,
                                                 float* __restrict__ out) {
    const int b   = blockIdx.x;
    const int tid = threadIdx.x;
    __shared__ float s[2][NPTS];   // 32 KB
    __shared__ float red[1024];

    const float* m0 = nnmin + ((size_t)0 * BATCH + b) * NPTS;
    const float* m1 = nnmin + ((size_t)1 * BATCH + b) * NPTS;
    const float* q1 = nnmin + ((size_t)2 * BATCH + b) * NPTS;
    const float* q2 = nnmin + ((size_t)3 * BATCH + b) * NPTS;

    float acc;
    {
        const float4 c0 = ((const float4*)m0)[tid];
        const float4 c1 = ((const float4*)m1)[tid];
        acc = c0.x + c0.y + c0.z + c0.w + c1.x + c1.y + c1.z + c1.w;
    }

    const float4 u1 = ((const float4*)q1)[tid];
    const float4 u2 = ((const float4*)q2)[tid];
    float v1[4] = {u1.x, u1.y, u1.z, u1.w};
    float v2[4] = {u2.x, u2.y, u2.z, u2.w};
    const int base = tid * 4;

    for (int k = 2; k <= NPTS; k <<= 1) {
        if (k >= 512) {
#pragma unroll
            for (int e = 0; e < 4; ++e) { s[0][base + e] = v1[e]; s[1][base + e] = v2[e]; }
            __syncthreads();
            for (int j = k >> 1; j >= 256; j >>= 1) {
#pragma unroll
                for (int tt = 0; tt < 2; ++tt) {
                    const int t = tid + tt * 1024;
                    const int i = ((t & ~(j - 1)) << 1) | (t & (j - 1));
                    const int p = i | j;
                    const bool asc = ((i & k) == 0);
#pragma unroll
                    for (int a = 0; a < 2; ++a) {
                        const float A0 = s[a][i], C0 = s[a][p];
                        const float lo = fminf(A0, C0), hi = fmaxf(A0, C0);
                        s[a][i] = asc ? lo : hi;
                        s[a][p] = asc ? hi : lo;
                    }
                }
                __syncthreads();
            }
#pragma unroll
            for (int e = 0; e < 4; ++e) { v1[e] = s[0][base + e]; v2[e] = s[1][base + e]; }
        }
        for (int j = (k >> 1) > 128 ? 128 : (k >> 1); j >= 4; j >>= 1) {
            const int m = j >> 2;
#pragma unroll
            for (int e = 0; e < 4; ++e) {
                const int i = base + e;
                const bool keepmin = (((i & j) == 0) == ((i & k) == 0));
                const float p1 = __shfl_xor(v1[e], m, 64);
                v1[e] = keepmin ? fminf(v1[e], p1) : fmaxf(v1[e], p1);
                const float p2 = __shfl_xor(v2[e], m, 64);
                v2[e] = keepmin ? fminf(v2[e], p2) : fmaxf(v2[e], p2);
            }
        }
        if (k >= 4) {  // j=2: pairs (0,2),(1,3); direction uniform within thread
            const bool asc2 = ((base & k) == 0);
            float lo = fminf(v1[0], v1[2]), hi = fmaxf(v1[0], v1[2]);
            v1[0] = asc2 ? lo : hi; v1[2] = asc2 ? hi : lo;
            lo = fminf(v1[1], v1[3]); hi = fmaxf(v1[1], v1[3]);
            v1[1] = asc2 ? lo : hi; v1[3] = asc2 ? hi : lo;
            lo = fminf(v2[0], v2[2]); hi = fmaxf(v2[0], v2[2]);
            v2[0] = asc2 ? lo : hi; v2[2] = asc2 ? hi : lo;
            lo = fminf(v2[1], v2[3]); hi = fmaxf(v2[1], v2[3]);
            v2[1] = asc2 ? lo : hi; v2[3] = asc2 ? hi : lo;
        }
        {  // j=1: pairs (0,1),(2,3)
            const bool ascA = (((base + 0) & k) == 0);
            const bool ascB = (((base + 2) & k) == 0);
            float lo = fminf(v1[0], v1[1]), hi = fmaxf(v1[0], v1[1]);
            v1[0] = ascA ? lo : hi; v1[1] = ascA ? hi : lo;
            lo = fminf(v1[2], v1[3]); hi = fmaxf(v1[2], v1[3]);
            v1[2] = ascB ? lo : hi; v1[3] = ascB ? hi : lo;
            lo = fminf(v2[0], v2[1]); hi = fmaxf(v2[0], v2[1]);
            v2[0] = ascA ? lo : hi; v2[1] = ascA ? hi : lo;
            lo = fminf(v2[2], v2[3]); hi = fmaxf(v2[2], v2[3]);
            v2[2] = ascB ? lo : hi; v2[3] = ascB ? hi : lo;
        }
    }

#pragma unroll
    for (int e = 0; e < 4; ++e) {
        const float d = v1[e] - v2[e];
        acc = fmaf(d, d, acc);  // ALPHA = 1
    }

    red[tid] = acc;
    __syncthreads();
    for (int sft = 512; sft > 0; sft >>= 1) {
        if (tid < sft) red[tid] += red[tid + sft];
        __syncthreads();
    }
    if (tid == 0) out[b] = red[0];
}

extern "C" void kernel_launch(void* const* d_in, const int* in_sizes, int n_in,
                              void* d_out, int out_size, void* d_ws, size_t ws_size,
                              hipStream_t stream) {
    const float* gts   = (const float*)d_in[0];
    const float* preds = (const float*)d_in[1];
    float* out   = (float*)d_out;
    float* nnmin = (float*)d_ws;  // 4*BATCH*NPTS floats = 256 KB

    dim3 grid(NCH, 4, BATCH);  // 32 stripes x 4 passes x 4 batches = 512 blocks
    nn_pass<<<grid, NTHR, 0, stream>>>(gts, preds, nnmin);
    nn_final<<<BATCH, 1024, 0, stream>>>(nnmin, out);
}